// Round 4
// baseline (74.505 us; speedup 1.0000x reference)
//
#include <hip/hip_runtime.h>

#define RES 96
#define CENTER 48
#define NPIX (RES * RES)
#define EPSF 1e-5f
#define MAXE 9472  // 9216 rounded up to a multiple of 256 (padded entry slots)

// Kernel A: compact strictly-positive boundary values into a (bi, bj, w, 0)
// float4 list in d_ws. Wave-level ballot/popc prefix + one global atomicAdd
// per wave. Order across waves is nondeterministic -> only permutes the fp
// sum (harmless at 0.199 abs threshold). The entry region was pre-zeroed by
// hipMemsetAsync, so unwritten tail slots read as w=0 and contribute nothing.
__global__ __launch_bounds__(256) void compact_kernel(const float* __restrict__ src,
                                                      int* __restrict__ cnt,
                                                      float4* __restrict__ entries) {
    const int s = blockIdx.x * 256 + threadIdx.x;  // 36 blocks x 256 = 9216
    const int lane = threadIdx.x & 63;
    const float b = src[s];
    const bool pos = b > 0.0f;
    const unsigned long long mask = __ballot(pos);
    int base = 0;
    if (lane == 0) base = atomicAdd(cnt, __popcll(mask));
    base = __shfl(base, 0, 64);
    if (pos) {
        const int idx = base + __popcll(mask & ((1ull << lane) - 1ull));
        const int bi = s / RES;
        const int bj = s - bi * RES;
        entries[idx] = make_float4((float)bi, (float)bj, b, 0.0f);
    }
}

// Kernel B: 4 pixels per 256-thread block (one wave each), sweeping only the
// compacted positive sources (~4600 instead of 9216). Each lane takes 4
// entries per iteration (coalesced float4 loads at +0/+64/+128/+192), one
// reciprocal per 4 terms via rational combining.
__global__ __launch_bounds__(256) void topos_kernel(const float* __restrict__ src,
                                                    const int* __restrict__ cntp,
                                                    const float4* __restrict__ entries,
                                                    float* __restrict__ out) {
    const int wave = threadIdx.x >> 6;
    const int lane = threadIdx.x & 63;
    const int pix = blockIdx.x * 4 + wave;
    const int i = pix / RES;
    const int j = pix - i * RES;

    const int di0 = i - CENTER;
    const int dj0 = j - CENTER;
    const int r2i = di0 * di0 + dj0 * dj0;

    if (r2i >= (CENTER - 1) * (CENTER - 1)) {
        // rim: pass boundary value through (wave-uniform branch)
        if (lane == 0) out[pix] = src[pix];
        return;
    }

    const float z = (float)CENTER - sqrtf((float)r2i) + EPSF;
    const float z2 = z * z;  // >= ~1.02 for interior pixels -> denoms positive
    const float fi = (float)i;
    const float fj = (float)j;

    const int niter = (*cntp + 255) >> 8;  // wave-uniform loop bound

    const float4* p = entries + lane;
    float acc = 0.0f;

    for (int it = 0; it < niter; ++it, p += 256) {
        const float4 e0 = p[0];
        const float4 e1 = p[64];
        const float4 e2 = p[128];
        const float4 e3 = p[192];

        const float x0 = fi - e0.x, y0 = fj - e0.y;
        const float x1 = fi - e1.x, y1 = fj - e1.y;
        const float x2 = fi - e2.x, y2 = fj - e2.y;
        const float x3 = fi - e3.x, y3 = fj - e3.y;

        const float d0 = fmaf(x0, x0, fmaf(y0, y0, z2));
        const float d1 = fmaf(x1, x1, fmaf(y1, y1, z2));
        const float d2 = fmaf(x2, x2, fmaf(y2, y2, z2));
        const float d3 = fmaf(x3, x3, fmaf(y3, y3, z2));

        // w0/d0 + w1/d1 + w2/d2 + w3/d3 = num / (d0 d1 d2 d3), one rcp.
        // d in [~1, ~2.1e4] -> den <= ~2e17, well inside fp32 range.
        const float d01 = d0 * d1;
        const float d23 = d2 * d3;
        const float n01 = fmaf(e0.z, d1, e1.z * d0);
        const float n23 = fmaf(e2.z, d3, e3.z * d2);
        const float num = fmaf(n01, d23, n23 * d01);
        const float den = d01 * d23;
        acc = fmaf(num, __builtin_amdgcn_rcpf(den), acc);
    }

    // wave reduction across 64 lanes
    #pragma unroll
    for (int off = 32; off > 0; off >>= 1)
        acc += __shfl_down(acc, off, 64);

    if (lane == 0) out[pix] = acc;
}

extern "C" void kernel_launch(void* const* d_in, const int* in_sizes, int n_in,
                              void* d_out, int out_size, void* d_ws, size_t ws_size,
                              hipStream_t stream) {
    const float* src = (const float*)d_in[0];
    float* out = (float*)d_out;
    int* cnt = (int*)d_ws;
    float4* entries = (float4*)((char*)d_ws + 16);

    // zero count + all padded entry slots (replaces the 0xAA poison so the
    // sweep needs no tail guards; ~152 KB, negligible)
    hipMemsetAsync(d_ws, 0, 16 + MAXE * sizeof(float4), stream);
    compact_kernel<<<NPIX / 256, 256, 0, stream>>>(src, cnt, entries);
    topos_kernel<<<NPIX / 4, 256, 0, stream>>>(src, cnt, entries, out);
}

// Round 5
// 65.809 us; speedup vs baseline: 1.1321x; 1.1321x over previous
//
#include <hip/hip_runtime.h>

#define RES 96
#define CENTER 48
#define NPIX (RES * RES)
#define EPSF 1e-5f

// One wave computes FOUR same-row consecutive pixels (pix0 = grp*4; 4 | 96 so a
// group never crosses a row). R3 was L1-BW-bound (each pixel-wave re-read the
// full 36 KB src); 4 pixels/wave cuts source traffic 4x and shares fdi / w-max
// / wrap logic / the v-table across pixels. Lane sweeps quads of 4 consecutive
// sources (coalesced float4, never straddling a row since 96 % 4 == 0); one
// rcp per 4 sources per pixel via rational combining. Single dispatch (R4
// lesson: every extra dispatch costs ~3-5 us in the timed window).
__global__ __launch_bounds__(256) void topos_kernel(const float* __restrict__ src,
                                                    float* __restrict__ out) {
    const int lane = threadIdx.x & 63;
    const int grp = blockIdx.x * 4 + (threadIdx.x >> 6);  // 0..2303
    const int pix0 = grp * 4;
    const int i = pix0 / RES;           // all 4 pixels share this row
    const int j0 = pix0 - i * RES;      // multiple of 4

    // per-pixel rim flag and z^2
    bool rim[4];
    float z2[4];
    bool allrim = true;
    #pragma unroll
    for (int p = 0; p < 4; ++p) {
        const int dj = j0 + p - CENTER;
        const int r2 = (i - CENTER) * (i - CENTER) + dj * dj;
        rim[p] = r2 >= (CENTER - 1) * (CENTER - 1);   // exact int test
        allrim &= rim[p];
        const float z = (float)CENTER - sqrtf((float)r2) + EPSF;
        z2[p] = z * z;
    }

    if (allrim) {  // wave-uniform: whole group is rim -> pure pass-through
        if (lane == 0) {
            #pragma unroll
            for (int p = 0; p < 4; ++p) out[pix0 + p] = src[pix0 + p];
        }
        return;
    }

    // lane's quad of sources starts at s0 = lane*4; advances +256 floats/iter
    const int s0 = lane * 4;
    const int biq0 = s0 / RES;             // 0..2
    const int bjq0 = s0 - biq0 * RES;
    float fdi = (float)(i - biq0);         // shared by all 4 pixels (same row)
    float y = (float)(j0 - bjq0);          // pixel-0 col delta to quad start
    const float wraplim = (float)(j0 - 95);
    const float* ptr = src + s0;

    float acc0 = 0.f, acc1 = 0.f, acc2 = 0.f, acc3 = 0.f;

    #pragma unroll 4
    for (int it = 0; it < NPIX / 256; ++it) {  // 36 iterations
        const float4 b4 = *(const float4*)ptr;
        ptr += 256;
        const float w0 = fmaxf(b4.x, 0.f);
        const float w1 = fmaxf(b4.y, 0.f);
        const float w2 = fmaxf(b4.z, 0.f);
        const float w3 = fmaxf(b4.w, 0.f);

        const float s2 = fdi * fdi;
        // u_{p,k} = y + (p - k), p,k in [0,3] -> 7 distinct values
        const float vm3 = y - 3.f, vm2 = y - 2.f, vm1 = y - 1.f;
        const float vp1 = y + 1.f, vp2 = y + 2.f, vp3 = y + 3.f;

        // pixel 0: u = { y, vm1, vm2, vm3 }
        {
            const float t = s2 + z2[0];
            const float d0 = fmaf(y, y, t),     d1 = fmaf(vm1, vm1, t);
            const float d2 = fmaf(vm2, vm2, t), d3 = fmaf(vm3, vm3, t);
            const float d01 = d0 * d1, d23 = d2 * d3;
            const float n01 = fmaf(w0, d1, w1 * d0);
            const float n23 = fmaf(w2, d3, w3 * d2);
            acc0 = fmaf(fmaf(n01, d23, n23 * d01),
                        __builtin_amdgcn_rcpf(d01 * d23), acc0);
        }
        // pixel 1: u = { vp1, y, vm1, vm2 }
        {
            const float t = s2 + z2[1];
            const float d0 = fmaf(vp1, vp1, t), d1 = fmaf(y, y, t);
            const float d2 = fmaf(vm1, vm1, t), d3 = fmaf(vm2, vm2, t);
            const float d01 = d0 * d1, d23 = d2 * d3;
            const float n01 = fmaf(w0, d1, w1 * d0);
            const float n23 = fmaf(w2, d3, w3 * d2);
            acc1 = fmaf(fmaf(n01, d23, n23 * d01),
                        __builtin_amdgcn_rcpf(d01 * d23), acc1);
        }
        // pixel 2: u = { vp2, vp1, y, vm1 }
        {
            const float t = s2 + z2[2];
            const float d0 = fmaf(vp2, vp2, t), d1 = fmaf(vp1, vp1, t);
            const float d2 = fmaf(y, y, t),     d3 = fmaf(vm1, vm1, t);
            const float d01 = d0 * d1, d23 = d2 * d3;
            const float n01 = fmaf(w0, d1, w1 * d0);
            const float n23 = fmaf(w2, d3, w3 * d2);
            acc2 = fmaf(fmaf(n01, d23, n23 * d01),
                        __builtin_amdgcn_rcpf(d01 * d23), acc2);
        }
        // pixel 3: u = { vp3, vp2, vp1, y }
        {
            const float t = s2 + z2[3];
            const float d0 = fmaf(vp3, vp3, t), d1 = fmaf(vp2, vp2, t);
            const float d2 = fmaf(vp1, vp1, t), d3 = fmaf(y, y, t);
            const float d01 = d0 * d1, d23 = d2 * d3;
            const float n01 = fmaf(w0, d1, w1 * d0);
            const float n23 = fmaf(w2, d3, w3 * d2);
            acc3 = fmaf(fmaf(n01, d23, n23 * d01),
                        __builtin_amdgcn_rcpf(d01 * d23), acc3);
        }

        // advance quad by 256 sources: bj += 64 (mod 96), bi += 2 (+1 on wrap)
        y -= 64.f;
        const bool wr = y < wraplim;
        y = wr ? y + 96.f : y;
        fdi -= wr ? 3.f : 2.f;
    }

    // wave reductions (4 independent chains interleave)
    #pragma unroll
    for (int off = 32; off > 0; off >>= 1) {
        acc0 += __shfl_down(acc0, off, 64);
        acc1 += __shfl_down(acc1, off, 64);
        acc2 += __shfl_down(acc2, off, 64);
        acc3 += __shfl_down(acc3, off, 64);
    }

    if (lane == 0) {
        out[pix0 + 0] = rim[0] ? src[pix0 + 0] : acc0;
        out[pix0 + 1] = rim[1] ? src[pix0 + 1] : acc1;
        out[pix0 + 2] = rim[2] ? src[pix0 + 2] : acc2;
        out[pix0 + 3] = rim[3] ? src[pix0 + 3] : acc3;
    }
}

extern "C" void kernel_launch(void* const* d_in, const int* in_sizes, int n_in,
                              void* d_out, int out_size, void* d_ws, size_t ws_size,
                              hipStream_t stream) {
    const float* src = (const float*)d_in[0];
    float* out = (float*)d_out;
    // 2304 groups of 4 pixels, 4 groups (waves) per 256-thread block
    topos_kernel<<<NPIX / 16, 256, 0, stream>>>(src, out);
}

// Round 6
// 61.525 us; speedup vs baseline: 1.2110x; 1.0696x over previous
//
#include <hip/hip_runtime.h>

#define RES 96
#define CENTER 48
#define NPIX (RES * RES)
#define EPSF 1e-5f

// Block = 256 threads = 4 waves = ONE 4-pixel group (pix0 = blockIdx*4, same
// row since 4 | 96). Each wave sweeps a QUARTER of the 9216 sources: wave w
// starts its lane-quad at s0 = w*256 + lane*4 and strides +1024 floats for 9
// iterations (R5 imbalance fix: 2304 blocks = exactly 9 blocks/CU, 9216
// equal-length waves = 9/SIMD, ~8 resident waves/SIMD hide load latency).
// Quads are 4-aligned and 96 % 4 == 0 -> never straddle a row; +1024 advance
// is bj += 64 (mod 96), bi += 10 (+1 on wrap). One rcp per 4 sources per
// pixel via rational combining; u-table / fdi / w-max shared across the 4
// same-row pixels. Wave partials combine via shuffle-reduce + 16-float LDS.
__global__ __launch_bounds__(256) void topos_kernel(const float* __restrict__ src,
                                                    float* __restrict__ out) {
    const int tid = threadIdx.x;
    const int wave = tid >> 6;
    const int lane = tid & 63;
    const int pix0 = blockIdx.x * 4;     // 2304 groups
    const int i = pix0 / RES;            // all 4 pixels share this row
    const int j0 = pix0 - i * RES;       // multiple of 4

    __shared__ float partial[16];        // [wave][pixel]

    // per-pixel rim flag and z^2 (exact int rim test)
    float z2[4];
    bool allrim = true;
    #pragma unroll
    for (int p = 0; p < 4; ++p) {
        const int dj = j0 + p - CENTER;
        const int r2 = (i - CENTER) * (i - CENTER) + dj * dj;
        allrim &= (r2 >= (CENTER - 1) * (CENTER - 1));
        const float z = (float)CENTER - sqrtf((float)r2) + EPSF;
        z2[p] = z * z;
    }

    if (allrim) {  // whole group is rim: pure pass-through, block exits
        if (tid < 4) out[pix0 + tid] = src[pix0 + tid];
        return;
    }

    // wave w's lane-quad starts at s0 = w*256 + lane*4 (0..1020), strides 1024
    const int s0 = wave * 256 + lane * 4;
    const int biq0 = s0 / RES;           // 0..10
    const int bjq0 = s0 - biq0 * RES;
    float fdi = (float)(i - biq0);       // shared by all 4 pixels (same row)
    float y = (float)(j0 - bjq0);        // pixel-0 col delta to quad start
    const float wraplim = (float)(j0 - 95);
    const float* ptr = src + s0;

    float acc0 = 0.f, acc1 = 0.f, acc2 = 0.f, acc3 = 0.f;

    #pragma unroll 3
    for (int it = 0; it < 9; ++it, ptr += 1024) {
        const float4 b4 = *(const float4*)ptr;
        const float w0 = fmaxf(b4.x, 0.f);
        const float w1 = fmaxf(b4.y, 0.f);
        const float w2 = fmaxf(b4.z, 0.f);
        const float w3 = fmaxf(b4.w, 0.f);

        const float s2 = fdi * fdi;
        // u_{p,k} = y + (p - k), p,k in [0,3] -> 7 distinct values
        const float vm3 = y - 3.f, vm2 = y - 2.f, vm1 = y - 1.f;
        const float vp1 = y + 1.f, vp2 = y + 2.f, vp3 = y + 3.f;

        // pixel 0: u = { y, vm1, vm2, vm3 }
        {
            const float t = s2 + z2[0];
            const float d0 = fmaf(y, y, t),     d1 = fmaf(vm1, vm1, t);
            const float d2 = fmaf(vm2, vm2, t), d3 = fmaf(vm3, vm3, t);
            const float d01 = d0 * d1, d23 = d2 * d3;
            const float n01 = fmaf(w0, d1, w1 * d0);
            const float n23 = fmaf(w2, d3, w3 * d2);
            acc0 = fmaf(fmaf(n01, d23, n23 * d01),
                        __builtin_amdgcn_rcpf(d01 * d23), acc0);
        }
        // pixel 1: u = { vp1, y, vm1, vm2 }
        {
            const float t = s2 + z2[1];
            const float d0 = fmaf(vp1, vp1, t), d1 = fmaf(y, y, t);
            const float d2 = fmaf(vm1, vm1, t), d3 = fmaf(vm2, vm2, t);
            const float d01 = d0 * d1, d23 = d2 * d3;
            const float n01 = fmaf(w0, d1, w1 * d0);
            const float n23 = fmaf(w2, d3, w3 * d2);
            acc1 = fmaf(fmaf(n01, d23, n23 * d01),
                        __builtin_amdgcn_rcpf(d01 * d23), acc1);
        }
        // pixel 2: u = { vp2, vp1, y, vm1 }
        {
            const float t = s2 + z2[2];
            const float d0 = fmaf(vp2, vp2, t), d1 = fmaf(vp1, vp1, t);
            const float d2 = fmaf(y, y, t),     d3 = fmaf(vm1, vm1, t);
            const float d01 = d0 * d1, d23 = d2 * d3;
            const float n01 = fmaf(w0, d1, w1 * d0);
            const float n23 = fmaf(w2, d3, w3 * d2);
            acc2 = fmaf(fmaf(n01, d23, n23 * d01),
                        __builtin_amdgcn_rcpf(d01 * d23), acc2);
        }
        // pixel 3: u = { vp3, vp2, vp1, y }
        {
            const float t = s2 + z2[3];
            const float d0 = fmaf(vp3, vp3, t), d1 = fmaf(vp2, vp2, t);
            const float d2 = fmaf(vp1, vp1, t), d3 = fmaf(y, y, t);
            const float d01 = d0 * d1, d23 = d2 * d3;
            const float n01 = fmaf(w0, d1, w1 * d0);
            const float n23 = fmaf(w2, d3, w3 * d2);
            acc3 = fmaf(fmaf(n01, d23, n23 * d01),
                        __builtin_amdgcn_rcpf(d01 * d23), acc3);
        }

        // advance quad by 1024 sources: bj += 64 (mod 96), bi += 10 (+1 wrap)
        y -= 64.f;
        const bool wr = y < wraplim;
        y = wr ? y + 96.f : y;
        fdi -= wr ? 11.f : 10.f;
    }

    // wave reductions (4 independent chains interleave)
    #pragma unroll
    for (int off = 32; off > 0; off >>= 1) {
        acc0 += __shfl_down(acc0, off, 64);
        acc1 += __shfl_down(acc1, off, 64);
        acc2 += __shfl_down(acc2, off, 64);
        acc3 += __shfl_down(acc3, off, 64);
    }

    if (lane == 0) {
        partial[wave * 4 + 0] = acc0;
        partial[wave * 4 + 1] = acc1;
        partial[wave * 4 + 2] = acc2;
        partial[wave * 4 + 3] = acc3;
    }
    __syncthreads();

    if (tid < 4) {
        const float sum = (partial[tid] + partial[4 + tid])
                        + (partial[8 + tid] + partial[12 + tid]);
        // recompute this pixel's rim flag (exact int test)
        const int dj = j0 + tid - CENTER;
        const int r2 = (i - CENTER) * (i - CENTER) + dj * dj;
        const bool rim = r2 >= (CENTER - 1) * (CENTER - 1);
        out[pix0 + tid] = rim ? src[pix0 + tid] : sum;
    }
}

extern "C" void kernel_launch(void* const* d_in, const int* in_sizes, int n_in,
                              void* d_out, int out_size, void* d_ws, size_t ws_size,
                              hipStream_t stream) {
    const float* src = (const float*)d_in[0];
    float* out = (float*)d_out;
    // 2304 blocks (one 4-pixel group each) = exactly 9 blocks/CU on 256 CUs
    topos_kernel<<<NPIX / 4, 256, 0, stream>>>(src, out);
}